// Round 2
// baseline (699.402 us; speedup 1.0000x reference)
//
#include <hip/hip_runtime.h>
#include <hip/hip_bf16.h>

typedef __bf16 bf16x8_t __attribute__((ext_vector_type(8)));
typedef float  f32x4_t  __attribute__((ext_vector_type(4)));

#define B_     2
#define L_     2048
#define D_     2048
#define H_     16
#define DH_    128
#define INNER_ 2048
#define M_     (B_ * L_)

// async global->LDS, 16B per lane. LDS dest must be wave-uniform base + lane*16.
__device__ __forceinline__ void gld_lds16(const void* g, void* l) {
    __builtin_amdgcn_global_load_lds(
        (const __attribute__((address_space(1))) void*)g,
        (__attribute__((address_space(3))) void*)l,
        16, 0, 0);
}

__device__ __forceinline__ unsigned short f2bf(float f) {
    __hip_bfloat16 h = __float2bfloat16(f);
    return *(unsigned short*)&h;
}
__device__ __forceinline__ float bf2f(unsigned short s) {
    return __uint_as_float(((unsigned)s) << 16);
}

// ---------------------------------------------------------------- cast f32 -> bf16
// n must be a multiple of 1024; 4 elements/thread.
__global__ __launch_bounds__(256)
void k_cast(const float* __restrict__ in, unsigned short* __restrict__ out) {
    const size_t i = ((size_t)blockIdx.x * 256 + threadIdx.x) * 4;
    float4 v = *(const float4*)(in + i);
    ushort4 o;
    o.x = f2bf(v.x); o.y = f2bf(v.y); o.z = f2bf(v.z); o.w = f2bf(v.w);
    *(ushort4*)(out + i) = o;
}

// ---------------------------------------------------------------- transpose+cast
// 2048x2048: f32 in -> bf16 out, transposed. 32x32 tiles, grid (64,64), block 256.
__global__ __launch_bounds__(256)
void k_transpose_cast(const float* __restrict__ in, unsigned short* __restrict__ out) {
    __shared__ unsigned short tile[32][33];
    const int t  = threadIdx.x;
    const int r  = t >> 3;          // 0..31
    const int c4 = (t & 7) << 2;    // 0,4,..,28
    const size_t ib = ((size_t)blockIdx.y * 32 + r) * 2048 + blockIdx.x * 32 + c4;
    float4 v = *(const float4*)(in + ib);
    tile[r][c4 + 0] = f2bf(v.x); tile[r][c4 + 1] = f2bf(v.y);
    tile[r][c4 + 2] = f2bf(v.z); tile[r][c4 + 3] = f2bf(v.w);
    __syncthreads();
    ushort4 o;
    o.x = tile[c4 + 0][r]; o.y = tile[c4 + 1][r];
    o.z = tile[c4 + 2][r]; o.w = tile[c4 + 3][r];
    const size_t ob = ((size_t)blockIdx.x * 32 + r) * 2048 + blockIdx.y * 32 + c4;
    *(ushort4*)(out + ob) = o;
}

// ---------------------------------------------------------------- transpose (bf16)
__global__ __launch_bounds__(256)
void k_transpose2048(const unsigned short* __restrict__ in,
                     unsigned short* __restrict__ out) {
    __shared__ unsigned short tile[32][33];
    const int t  = threadIdx.x;
    const int r  = t >> 3;
    const int c4 = (t & 7) << 2;
    const size_t ib = ((size_t)blockIdx.y * 32 + r) * 2048 + blockIdx.x * 32 + c4;
    ushort4 v = *(const ushort4*)(in + ib);
    tile[r][c4 + 0] = v.x; tile[r][c4 + 1] = v.y;
    tile[r][c4 + 2] = v.z; tile[r][c4 + 3] = v.w;
    __syncthreads();
    ushort4 o;
    o.x = tile[c4 + 0][r]; o.y = tile[c4 + 1][r];
    o.z = tile[c4 + 2][r]; o.w = tile[c4 + 3][r];
    const size_t ob = ((size_t)blockIdx.x * 32 + r) * 2048 + blockIdx.y * 32 + c4;
    *(ushort4*)(out + ob) = o;
}

// ---------------------------------------------------------------- GEMM
// C[M][N] = A[M][K] @ Bt[N][K]^T + bias(f32), bf16 A/B, fp32 accum, OutT out.
// 128x128 tile / block of 256 (4 waves, 64x64 each), BK=32, 16x16x32 MFMA.
template <typename OutT>
__global__ __launch_bounds__(256)
void k_gemm_bt(const __hip_bfloat16* __restrict__ A,
               const __hip_bfloat16* __restrict__ Bt,
               const float* __restrict__ bias,
               OutT* __restrict__ C,
               int M, int N, int K) {
    __shared__ __align__(16) __hip_bfloat16 As[128 * 32];
    __shared__ __align__(16) __hip_bfloat16 Bs[128 * 32];
    const int t    = threadIdx.x;
    const int lane = t & 63;
    const int wave = t >> 6;
    const int quad = lane >> 4;
    const int l16  = lane & 15;
    const int wm   = (wave >> 1) * 64;
    const int wn   = (wave & 1) * 64;
    const int tileM = blockIdx.x * 128;
    const int tileN = blockIdx.y * 128;

    const int srow = t >> 2;         // 0..63
    const int scol = (t & 3) << 3;   // 0,8,16,24
    const __hip_bfloat16* Ag = A  + (size_t)(tileM + srow) * K + scol;
    const __hip_bfloat16* Bg = Bt + (size_t)(tileN + srow) * K + scol;
    __hip_bfloat16* Asl  = &As[t * 8];          // byte offset t*16 (wave base + lane*16)
    __hip_bfloat16* Asl2 = &As[2048 + t * 8];
    __hip_bfloat16* Bsl  = &Bs[t * 8];
    __hip_bfloat16* Bsl2 = &Bs[2048 + t * 8];
    const size_t rowskip = (size_t)64 * K;

    f32x4_t acc[4][4];
#pragma unroll
    for (int i = 0; i < 4; i++)
#pragma unroll
        for (int j = 0; j < 4; j++) acc[i][j] = (f32x4_t){0.f, 0.f, 0.f, 0.f};

    for (int k0 = 0; k0 < K; k0 += 32) {
        __syncthreads();
        gld_lds16(Ag + k0,           Asl);
        gld_lds16(Ag + rowskip + k0, Asl2);
        gld_lds16(Bg + k0,           Bsl);
        gld_lds16(Bg + rowskip + k0, Bsl2);
        __syncthreads();

        bf16x8_t af[4], bfr[4];
#pragma unroll
        for (int i = 0; i < 4; i++)
            af[i] = *(const bf16x8_t*)&As[(wm + i * 16 + l16) * 32 + quad * 8];
#pragma unroll
        for (int j = 0; j < 4; j++)
            bfr[j] = *(const bf16x8_t*)&Bs[(wn + j * 16 + l16) * 32 + quad * 8];
#pragma unroll
        for (int i = 0; i < 4; i++)
#pragma unroll
            for (int j = 0; j < 4; j++)
                acc[i][j] = __builtin_amdgcn_mfma_f32_16x16x32_bf16(
                    af[i], bfr[j], acc[i][j], 0, 0, 0);
    }

#pragma unroll
    for (int i = 0; i < 4; i++) {
#pragma unroll
        for (int r = 0; r < 4; r++) {
            const int m = tileM + wm + i * 16 + quad * 4 + r;
#pragma unroll
            for (int j = 0; j < 4; j++) {
                const int n = tileN + wn + j * 16 + l16;
                float val = acc[i][j][r] + bias[n];
                if constexpr (__is_same(OutT, float))
                    C[(size_t)m * N + n] = val;
                else
                    C[(size_t)m * N + n] = __float2bfloat16(val);
            }
        }
    }
}

// ---------------------------------------------------------------- RMSNorm + RoPE
// One block per row (M rows of 2048). In-place on bf16 buf. f32 aux inputs.
// lls == nullptr for k (no logit scale).
__global__ __launch_bounds__(256)
void k_rmsrope(__hip_bfloat16* __restrict__ buf,
               const float* __restrict__ w,
               const float* __restrict__ pcos,
               const float* __restrict__ psin,
               const float* __restrict__ lls,
               float extra) {
    const int row = blockIdx.x;
    const int l   = row & (L_ - 1);
    const int t   = threadIdx.x;
    __hip_bfloat16* p = buf + (size_t)row * INNER_ + t * 8;

    float x[8];
    {
        const unsigned short* ps = (const unsigned short*)p;
        ushort4 a = *(const ushort4*)ps;
        ushort4 b = *(const ushort4*)(ps + 4);
        unsigned short s[8] = {a.x, a.y, a.z, a.w, b.x, b.y, b.z, b.w};
#pragma unroll
        for (int i = 0; i < 8; i++) x[i] = bf2f(s[i]);
    }
    float ss = 0.f;
#pragma unroll
    for (int i = 0; i < 8; i++) ss += x[i] * x[i];
#pragma unroll
    for (int off = 32; off >= 1; off >>= 1) ss += __shfl_down(ss, off);
    __shared__ float red[4];
    if ((t & 63) == 0) red[t >> 6] = ss;
    __syncthreads();
    ss = red[0] + red[1] + red[2] + red[3];
    const float rstd = rsqrtf(ss * (1.0f / (float)INNER_) + 1e-6f);

    float scale = extra;
    if (lls) scale *= lls[l];

    const float4 c4 = ((const float4*)(pcos + (size_t)l * (INNER_ / 2)))[t];
    const float4 s4 = ((const float4*)(psin + (size_t)l * (INNER_ / 2)))[t];
    const float cc[4] = {c4.x, c4.y, c4.z, c4.w};
    const float sn[4] = {s4.x, s4.y, s4.z, s4.w};
    const float4 w0 = ((const float4*)w)[t * 2];
    const float4 w1 = ((const float4*)w)[t * 2 + 1];
    const float ww[8] = {w0.x, w0.y, w0.z, w0.w, w1.x, w1.y, w1.z, w1.w};

    union { __hip_bfloat16 h[8]; uint4 u; } pk;
#pragma unroll
    for (int pi = 0; pi < 4; pi++) {
        const float y1 = x[pi * 2]     * rstd * ww[pi * 2];
        const float y2 = x[pi * 2 + 1] * rstd * ww[pi * 2 + 1];
        pk.h[pi * 2]     = __float2bfloat16((y1 * cc[pi] - y2 * sn[pi]) * scale);
        pk.h[pi * 2 + 1] = __float2bfloat16((y1 * sn[pi] + y2 * cc[pi]) * scale);
    }
    *(uint4*)p = pk.u;
}

// ---------------------------------------------------------------- attention
// Causal flash attention. grid (L/64, B*H). Block 256 = 4 waves, each wave
// owns 16 q-rows. q pre-scaled by lls * rsqrt(Dh) * log2(e).
// q,k: [M][INNER] bf16 ; vT: [b*H+h][Dh][L] bf16 ; o: [M][INNER] bf16.
__global__ __launch_bounds__(256)
void k_attn(const __hip_bfloat16* __restrict__ q,
            const __hip_bfloat16* __restrict__ k,
            const __hip_bfloat16* __restrict__ vT,
            __hip_bfloat16* __restrict__ o) {
    __shared__ __align__(16) __hip_bfloat16 Ks[64 * 128];   // [key][d]
    __shared__ __align__(16) __hip_bfloat16 Vs[128 * 64];   // [d][key]
    __shared__ __align__(16) __hip_bfloat16 Ps[4][16 * 64]; // per-wave P tile

    const int qt = blockIdx.x;
    const int bh = blockIdx.y;   // b*16+h
    const int b  = bh >> 4;
    const int h  = bh & 15;
    const int t = threadIdx.x, wave = t >> 6, lane = t & 63;
    const int quad = lane >> 4, l16 = lane & 15;

    bf16x8_t aq[4];
    {
        const size_t qoff = (size_t)(b * L_ + qt * 64 + wave * 16 + l16) * INNER_ + h * DH_;
#pragma unroll
        for (int kk = 0; kk < 4; kk++)
            aq[kk] = *(const bf16x8_t*)(q + qoff + kk * 32 + quad * 8);
    }

    f32x4_t oacc[8];
#pragma unroll
    for (int jj = 0; jj < 8; jj++) oacc[jj] = (f32x4_t){0.f, 0.f, 0.f, 0.f};
    float mrow[4] = {-1e30f, -1e30f, -1e30f, -1e30f};
    float lrow[4] = {0.f, 0.f, 0.f, 0.f};

    const int krow = t >> 4, kcol = (t & 15) << 3;
    const int vrow = t >> 3, vcol = (t & 7) << 3;

    for (int kt = 0; kt <= qt; ++kt) {
        const int kv0 = kt * 64;
        __syncthreads();
#pragma unroll
        for (int i = 0; i < 4; i++) {
            gld_lds16(k  + (size_t)(b * L_ + kv0 + i * 16 + krow) * INNER_ + h * DH_ + kcol,
                      &Ks[t * 8 + i * 2048]);
            gld_lds16(vT + ((size_t)bh * DH_ + i * 32 + vrow) * L_ + kv0 + vcol,
                      &Vs[t * 8 + i * 2048]);
        }
        __syncthreads();

        f32x4_t sacc[4];
#pragma unroll
        for (int j = 0; j < 4; j++) sacc[j] = (f32x4_t){0.f, 0.f, 0.f, 0.f};
#pragma unroll
        for (int j = 0; j < 4; j++)
#pragma unroll
            for (int kk = 0; kk < 4; kk++) {
                bf16x8_t bk_ = *(const bf16x8_t*)&Ks[(j * 16 + l16) * 128 + kk * 32 + quad * 8];
                sacc[j] = __builtin_amdgcn_mfma_f32_16x16x32_bf16(aq[kk], bk_, sacc[j], 0, 0, 0);
            }

        if (kt == qt) {
            const int qbase = qt * 64 + wave * 16 + quad * 4;
#pragma unroll
            for (int j = 0; j < 4; j++) {
                const int key = kv0 + j * 16 + l16;
#pragma unroll
                for (int r = 0; r < 4; r++)
                    if (key > qbase + r) sacc[j][r] = -1e30f;
            }
        }

        float alpha[4];
#pragma unroll
        for (int r = 0; r < 4; r++) {
            float mx = fmaxf(fmaxf(sacc[0][r], sacc[1][r]), fmaxf(sacc[2][r], sacc[3][r]));
#pragma unroll
            for (int off = 1; off < 16; off <<= 1) mx = fmaxf(mx, __shfl_xor(mx, off));
            const float mnew = fmaxf(mrow[r], mx);
            alpha[r] = exp2f(mrow[r] - mnew);
            float s0 = 0.f;
#pragma unroll
            for (int j = 0; j < 4; j++) {
                const float pv = exp2f(sacc[j][r] - mnew);
                Ps[wave][(quad * 4 + r) * 64 + j * 16 + l16] = __float2bfloat16(pv);
                s0 += pv;
            }
#pragma unroll
            for (int off = 1; off < 16; off <<= 1) s0 += __shfl_xor(s0, off);
            lrow[r] = lrow[r] * alpha[r] + s0;
            mrow[r] = mnew;
        }

#pragma unroll
        for (int jj = 0; jj < 8; jj++)
#pragma unroll
            for (int r = 0; r < 4; r++) oacc[jj][r] *= alpha[r];

#pragma unroll
        for (int kk2 = 0; kk2 < 2; kk2++) {
            bf16x8_t ap = *(const bf16x8_t*)&Ps[wave][l16 * 64 + kk2 * 32 + quad * 8];
#pragma unroll
            for (int jj = 0; jj < 8; jj++) {
                bf16x8_t bv_ = *(const bf16x8_t*)&Vs[(jj * 16 + l16) * 64 + kk2 * 32 + quad * 8];
                oacc[jj] = __builtin_amdgcn_mfma_f32_16x16x32_bf16(ap, bv_, oacc[jj], 0, 0, 0);
            }
        }
    }

#pragma unroll
    for (int r = 0; r < 4; r++) {
        const int qi = qt * 64 + wave * 16 + quad * 4 + r;
        const float inv = 1.0f / lrow[r];
#pragma unroll
        for (int jj = 0; jj < 8; jj++) {
            const int d = jj * 16 + l16;
            o[(size_t)(b * L_ + qi) * INNER_ + h * DH_ + d] =
                __float2bfloat16(oacc[jj][r] * inv);
        }
    }
}

// ---------------------------------------------------------------- launch
extern "C" void kernel_launch(void* const* d_in, const int* in_sizes, int n_in,
                              void* d_out, int out_size, void* d_ws, size_t ws_size,
                              hipStream_t stream) {
    const float* x      = (const float*)d_in[0];
    const float* pe_cos = (const float*)d_in[1];
    const float* pe_sin = (const float*)d_in[2];
    const float* lls    = (const float*)d_in[3];
    const float* wq     = (const float*)d_in[4];
    const float* bq     = (const float*)d_in[5];
    const float* wk     = (const float*)d_in[6];
    const float* bk     = (const float*)d_in[7];
    const float* wv     = (const float*)d_in[8];
    const float* bv     = (const float*)d_in[9];
    const float* qn     = (const float*)d_in[10];
    const float* kn     = (const float*)d_in[11];
    const float* wo     = (const float*)d_in[12];
    const float* bo     = (const float*)d_in[13];

    char* ws = (char*)d_ws;
    const size_t SZ_W = (size_t)D_ * INNER_ * 2;   // 8 MB (bf16)
    const size_t SZ_M = (size_t)M_ * INNER_ * 2;   // 16 MB (bf16)
    __hip_bfloat16* xb  = (__hip_bfloat16*)ws;            ws += SZ_M;
    __hip_bfloat16* wqT = (__hip_bfloat16*)ws;            ws += SZ_W;
    __hip_bfloat16* wkT = (__hip_bfloat16*)ws;            ws += SZ_W;
    __hip_bfloat16* wvT = (__hip_bfloat16*)ws;            ws += SZ_W;
    __hip_bfloat16* woT = (__hip_bfloat16*)ws;            ws += SZ_W;
    __hip_bfloat16* qb  = (__hip_bfloat16*)ws;            ws += SZ_M;
    __hip_bfloat16* kb  = (__hip_bfloat16*)ws;            ws += SZ_M;
    __hip_bfloat16* vb  = (__hip_bfloat16*)ws;            ws += SZ_M;
    __hip_bfloat16* vT  = (__hip_bfloat16*)ws;            ws += SZ_M;
    __hip_bfloat16* ab  = (__hip_bfloat16*)ws;            ws += SZ_M;
    (void)in_sizes; (void)n_in; (void)out_size; (void)ws_size;

    const dim3 tb(256);
    const dim3 gT(64, 64);
    const dim3 gG(M_ / 128, INNER_ / 128);   // (32,16)

    // 0. cast x to bf16
    k_cast<<<(M_ * D_) / 1024, tb, 0, stream>>>(x, (unsigned short*)xb);

    // 1. transpose+cast weights to bf16 [N][K]
    k_transpose_cast<<<gT, tb, 0, stream>>>(wq, (unsigned short*)wqT);
    k_transpose_cast<<<gT, tb, 0, stream>>>(wk, (unsigned short*)wkT);
    k_transpose_cast<<<gT, tb, 0, stream>>>(wv, (unsigned short*)wvT);
    k_transpose_cast<<<gT, tb, 0, stream>>>(wo, (unsigned short*)woT);

    // 2. QKV projections (bf16 out)
    k_gemm_bt<__hip_bfloat16><<<gG, tb, 0, stream>>>(xb, wqT, bq, qb, M_, INNER_, D_);
    k_gemm_bt<__hip_bfloat16><<<gG, tb, 0, stream>>>(xb, wkT, bk, kb, M_, INNER_, D_);
    k_gemm_bt<__hip_bfloat16><<<gG, tb, 0, stream>>>(xb, wvT, bv, vb, M_, INNER_, D_);

    // 3. RMSNorm + RoPE (+ fold softmax scale, logit scale, log2e into q)
    const float qextra = 0.08838834764831843f /* rsqrt(128) */ * 1.4426950408889634f /* log2 e */;
    k_rmsrope<<<M_, tb, 0, stream>>>(qb, qn, pe_cos, pe_sin, lls, qextra);
    k_rmsrope<<<M_, tb, 0, stream>>>(kb, kn, pe_cos, pe_sin, nullptr, 1.0f);

    // 4. transpose v per batch (each batch is a 2048x2048 bf16 transpose)
    k_transpose2048<<<gT, tb, 0, stream>>>((const unsigned short*)vb, (unsigned short*)vT);
    k_transpose2048<<<gT, tb, 0, stream>>>((const unsigned short*)(vb + (size_t)L_ * INNER_),
                                           (unsigned short*)(vT + (size_t)L_ * INNER_));

    // 5. causal flash attention
    k_attn<<<dim3(L_ / 64, B_ * H_), tb, 0, stream>>>(qb, kb, vT, ab);

    // 6. output projection -> d_out (f32)
    k_gemm_bt<float><<<gG, tb, 0, stream>>>(ab, woT, bo, (float*)d_out, M_, D_, INNER_);
}

// Round 3
// 476.322 us; speedup vs baseline: 1.4683x; 1.4683x over previous
//
#include <hip/hip_runtime.h>
#include <hip/hip_bf16.h>

typedef __bf16 bf16x8_t __attribute__((ext_vector_type(8)));
typedef float  f32x4_t  __attribute__((ext_vector_type(4)));

#define B_     2
#define L_     2048
#define D_     2048
#define H_     16
#define DH_    128
#define INNER_ 2048
#define M_     (B_ * L_)

// async global->LDS, 16B per lane. LDS dest must be wave-uniform base + lane*16.
__device__ __forceinline__ void gld_lds16(const void* g, void* l) {
    __builtin_amdgcn_global_load_lds(
        (const __attribute__((address_space(1))) void*)g,
        (__attribute__((address_space(3))) void*)l,
        16, 0, 0);
}

__device__ __forceinline__ unsigned short f2bf(float f) {
    __hip_bfloat16 h = __float2bfloat16(f);
    return *(unsigned short*)&h;
}
__device__ __forceinline__ float bf2f(unsigned short s) {
    return __uint_as_float(((unsigned)s) << 16);
}

// ---------------------------------------------------------------- cast f32 -> bf16
__global__ __launch_bounds__(256)
void k_cast(const float* __restrict__ in, unsigned short* __restrict__ out) {
    const size_t i = ((size_t)blockIdx.x * 256 + threadIdx.x) * 4;
    float4 v = *(const float4*)(in + i);
    ushort4 o;
    o.x = f2bf(v.x); o.y = f2bf(v.y); o.z = f2bf(v.z); o.w = f2bf(v.w);
    *(ushort4*)(out + i) = o;
}

// ---------------------------------------------------------------- transpose+cast
__global__ __launch_bounds__(256)
void k_transpose_cast(const float* __restrict__ in, unsigned short* __restrict__ out) {
    __shared__ unsigned short tile[32][33];
    const int t  = threadIdx.x;
    const int r  = t >> 3;
    const int c4 = (t & 7) << 2;
    const size_t ib = ((size_t)blockIdx.y * 32 + r) * 2048 + blockIdx.x * 32 + c4;
    float4 v = *(const float4*)(in + ib);
    tile[r][c4 + 0] = f2bf(v.x); tile[r][c4 + 1] = f2bf(v.y);
    tile[r][c4 + 2] = f2bf(v.z); tile[r][c4 + 3] = f2bf(v.w);
    __syncthreads();
    ushort4 o;
    o.x = tile[c4 + 0][r]; o.y = tile[c4 + 1][r];
    o.z = tile[c4 + 2][r]; o.w = tile[c4 + 3][r];
    const size_t ob = ((size_t)blockIdx.x * 32 + r) * 2048 + blockIdx.y * 32 + c4;
    *(ushort4*)(out + ob) = o;
}

// ---------------------------------------------------------------- transpose (bf16)
__global__ __launch_bounds__(256)
void k_transpose2048(const unsigned short* __restrict__ in,
                     unsigned short* __restrict__ out) {
    __shared__ unsigned short tile[32][33];
    const int t  = threadIdx.x;
    const int r  = t >> 3;
    const int c4 = (t & 7) << 2;
    const size_t ib = ((size_t)blockIdx.y * 32 + r) * 2048 + blockIdx.x * 32 + c4;
    ushort4 v = *(const ushort4*)(in + ib);
    tile[r][c4 + 0] = v.x; tile[r][c4 + 1] = v.y;
    tile[r][c4 + 2] = v.z; tile[r][c4 + 3] = v.w;
    __syncthreads();
    ushort4 o;
    o.x = tile[c4 + 0][r]; o.y = tile[c4 + 1][r];
    o.z = tile[c4 + 2][r]; o.w = tile[c4 + 3][r];
    const size_t ob = ((size_t)blockIdx.x * 32 + r) * 2048 + blockIdx.y * 32 + c4;
    *(ushort4*)(out + ob) = o;
}

// ---------------------------------------------------------------- GEMM core macro body
// 128x128 tile / block of 256 (4 waves, 64x64 each), BK=32, 16x16x32 MFMA.
// Computes acc[4][4] for tileM/tileN; A[M][K], Bt rows indexed globally.
#define GEMM_BODY(A_, Bt_, K_)                                                 \
    __shared__ __align__(16) __hip_bfloat16 As[128 * 32];                      \
    __shared__ __align__(16) __hip_bfloat16 Bs[128 * 32];                      \
    const int t    = threadIdx.x;                                              \
    const int lane = t & 63;                                                   \
    const int wave = t >> 6;                                                   \
    const int quad = lane >> 4;                                                \
    const int l16  = lane & 15;                                                \
    const int wm   = (wave >> 1) * 64;                                         \
    const int wn   = (wave & 1) * 64;                                          \
    const int srow = t >> 2;                                                   \
    const int scol = (t & 3) << 3;                                             \
    const __hip_bfloat16* Ag = A_  + (size_t)(tileM + srow) * K_ + scol;       \
    const __hip_bfloat16* Bg = Bt_ + (size_t)(tileN + srow) * K_ + scol;       \
    __hip_bfloat16* Asl  = &As[t * 8];                                         \
    __hip_bfloat16* Asl2 = &As[2048 + t * 8];                                  \
    __hip_bfloat16* Bsl  = &Bs[t * 8];                                         \
    __hip_bfloat16* Bsl2 = &Bs[2048 + t * 8];                                  \
    const size_t rowskip = (size_t)64 * K_;                                    \
    f32x4_t acc[4][4];                                                         \
    _Pragma("unroll") for (int i = 0; i < 4; i++)                              \
        _Pragma("unroll") for (int j = 0; j < 4; j++)                          \
            acc[i][j] = (f32x4_t){0.f, 0.f, 0.f, 0.f};                         \
    for (int k0 = 0; k0 < K_; k0 += 32) {                                      \
        __syncthreads();                                                       \
        gld_lds16(Ag + k0,           Asl);                                     \
        gld_lds16(Ag + rowskip + k0, Asl2);                                    \
        gld_lds16(Bg + k0,           Bsl);                                     \
        gld_lds16(Bg + rowskip + k0, Bsl2);                                    \
        __syncthreads();                                                       \
        bf16x8_t af[4], bfr[4];                                                \
        _Pragma("unroll") for (int i = 0; i < 4; i++)                          \
            af[i] = *(const bf16x8_t*)&As[(wm + i * 16 + l16) * 32 + quad * 8];\
        _Pragma("unroll") for (int j = 0; j < 4; j++)                          \
            bfr[j] = *(const bf16x8_t*)&Bs[(wn + j * 16 + l16) * 32 + quad * 8];\
        _Pragma("unroll") for (int i = 0; i < 4; i++)                          \
            _Pragma("unroll") for (int j = 0; j < 4; j++)                      \
                acc[i][j] = __builtin_amdgcn_mfma_f32_16x16x32_bf16(           \
                    af[i], bfr[j], acc[i][j], 0, 0, 0);                        \
    }

// wo GEMM: f32 output to d_out
__global__ __launch_bounds__(256)
void k_gemm_bt_f32(const __hip_bfloat16* __restrict__ A,
                   const __hip_bfloat16* __restrict__ Bt,
                   const float* __restrict__ bias,
                   float* __restrict__ C,
                   int M, int N, int K) {
    const int tileM = blockIdx.x * 128;
    const int tileN = blockIdx.y * 128;
    GEMM_BODY(A, Bt, K)
#pragma unroll
    for (int i = 0; i < 4; i++)
#pragma unroll
        for (int r = 0; r < 4; r++) {
            const int m = tileM + wm + i * 16 + quad * 4 + r;
#pragma unroll
            for (int j = 0; j < 4; j++) {
                const int n = tileN + wn + j * 16 + l16;
                C[(size_t)m * N + n] = acc[i][j][r] + bias[n];
            }
        }
}

// fused QKV GEMM: Bt is [3*INNER][D] (wq^T|wk^T|wv^T), grid.y = 48.
__global__ __launch_bounds__(256)
void k_gemm_qkv(const __hip_bfloat16* __restrict__ A,
                const __hip_bfloat16* __restrict__ Bt,
                const float* __restrict__ bq, const float* __restrict__ bk,
                const float* __restrict__ bv,
                __hip_bfloat16* __restrict__ qo, __hip_bfloat16* __restrict__ ko,
                __hip_bfloat16* __restrict__ vo) {
    const int tileM = blockIdx.x * 128;
    const int tileN = blockIdx.y * 128;          // global col in [0,6144)
    GEMM_BODY(A, Bt, D_)
    const int sel  = blockIdx.y >> 4;            // 0=q 1=k 2=v
    const int nbas = tileN - sel * INNER_;
    const float* bias = (sel == 0) ? bq : (sel == 1) ? bk : bv;
    __hip_bfloat16* C = (sel == 0) ? qo : (sel == 1) ? ko : vo;
#pragma unroll
    for (int i = 0; i < 4; i++)
#pragma unroll
        for (int r = 0; r < 4; r++) {
            const int m = tileM + wm + i * 16 + quad * 4 + r;
#pragma unroll
            for (int j = 0; j < 4; j++) {
                const int n = nbas + wn + j * 16 + l16;
                C[(size_t)m * INNER_ + n] = __float2bfloat16(acc[i][j][r] + bias[n]);
            }
        }
}

// ---------------------------------------------------------------- RMSNorm + RoPE
__global__ __launch_bounds__(256)
void k_rmsrope(__hip_bfloat16* __restrict__ buf,
               const float* __restrict__ w,
               const float* __restrict__ pcos,
               const float* __restrict__ psin,
               const float* __restrict__ lls,
               float extra) {
    const int row = blockIdx.x;
    const int l   = row & (L_ - 1);
    const int t   = threadIdx.x;
    __hip_bfloat16* p = buf + (size_t)row * INNER_ + t * 8;

    float x[8];
    {
        const unsigned short* ps = (const unsigned short*)p;
        ushort4 a = *(const ushort4*)ps;
        ushort4 b = *(const ushort4*)(ps + 4);
        unsigned short s[8] = {a.x, a.y, a.z, a.w, b.x, b.y, b.z, b.w};
#pragma unroll
        for (int i = 0; i < 8; i++) x[i] = bf2f(s[i]);
    }
    float ss = 0.f;
#pragma unroll
    for (int i = 0; i < 8; i++) ss += x[i] * x[i];
#pragma unroll
    for (int off = 32; off >= 1; off >>= 1) ss += __shfl_down(ss, off);
    __shared__ float red[4];
    if ((t & 63) == 0) red[t >> 6] = ss;
    __syncthreads();
    ss = red[0] + red[1] + red[2] + red[3];
    const float rstd = rsqrtf(ss * (1.0f / (float)INNER_) + 1e-6f);

    float scale = extra;
    if (lls) scale *= lls[l];

    const float4 c4 = ((const float4*)(pcos + (size_t)l * (INNER_ / 2)))[t];
    const float4 s4 = ((const float4*)(psin + (size_t)l * (INNER_ / 2)))[t];
    const float cc[4] = {c4.x, c4.y, c4.z, c4.w};
    const float sn[4] = {s4.x, s4.y, s4.z, s4.w};
    const float4 w0 = ((const float4*)w)[t * 2];
    const float4 w1 = ((const float4*)w)[t * 2 + 1];
    const float ww[8] = {w0.x, w0.y, w0.z, w0.w, w1.x, w1.y, w1.z, w1.w};

    union { __hip_bfloat16 h[8]; uint4 u; } pk;
#pragma unroll
    for (int pi = 0; pi < 4; pi++) {
        const float y1 = x[pi * 2]     * rstd * ww[pi * 2];
        const float y2 = x[pi * 2 + 1] * rstd * ww[pi * 2 + 1];
        pk.h[pi * 2]     = __float2bfloat16((y1 * cc[pi] - y2 * sn[pi]) * scale);
        pk.h[pi * 2 + 1] = __float2bfloat16((y1 * sn[pi] + y2 * cc[pi]) * scale);
    }
    *(uint4*)p = pk.u;
}

// ---------------------------------------------------------------- attention
// Causal flash attention, paired q-tiles for load balance: block p handles
// q-tiles p and 31-p -> exactly 33 K-tile iterations per block.
// LDS XOR-swizzle on Ks/Vs (chunk' = chunk ^ (row & mask)) -> uniform banks.
// grid (16, B*H). 4 waves x 16 q-rows.
__global__ __launch_bounds__(256)
void k_attn(const __hip_bfloat16* __restrict__ q,
            const __hip_bfloat16* __restrict__ k,
            const __hip_bfloat16* __restrict__ vT,
            __hip_bfloat16* __restrict__ o) {
    __shared__ __align__(16) __hip_bfloat16 Ks[64 * 128];   // [key][d] swizzled
    __shared__ __align__(16) __hip_bfloat16 Vs[128 * 64];   // [d][key] swizzled
    __shared__ __align__(16) __hip_bfloat16 Ps[4][16 * 72]; // per-wave, +8 pad

    const int p  = blockIdx.x;
    const int bh = blockIdx.y;
    const int b  = bh >> 4;
    const int h  = bh & 15;
    const int t = threadIdx.x, wave = t >> 6, lane = t & 63;
    const int quad = lane >> 4, l16 = lane & 15;

    // staging maps (with XOR chunk swizzle on the global side)
    const int krow = t >> 4;                         // 0..15
    const int kcol = ((t & 15) ^ krow) << 3;         // chunk = chunk' ^ (row&15)
    const int vrow = t >> 3;                         // 0..31
    const int vcol = ((t & 7) ^ (vrow & 7)) << 3;    // chunk = chunk' ^ (row&7)

    for (int half = 0; half < 2; ++half) {
        const int qt = half ? (31 - p) : p;

        bf16x8_t aq[4];
        {
            const size_t qoff = (size_t)(b * L_ + qt * 64 + wave * 16 + l16) * INNER_ + h * DH_;
#pragma unroll
            for (int kk = 0; kk < 4; kk++)
                aq[kk] = *(const bf16x8_t*)(q + qoff + kk * 32 + quad * 8);
        }

        f32x4_t oacc[8];
#pragma unroll
        for (int jj = 0; jj < 8; jj++) oacc[jj] = (f32x4_t){0.f, 0.f, 0.f, 0.f};
        float mrow[4] = {-1e30f, -1e30f, -1e30f, -1e30f};
        float lrow[4] = {0.f, 0.f, 0.f, 0.f};

        for (int kt = 0; kt <= qt; ++kt) {
            const int kv0 = kt * 64;
            __syncthreads();
#pragma unroll
            for (int i = 0; i < 4; i++) {
                gld_lds16(k  + (size_t)(b * L_ + kv0 + i * 16 + krow) * INNER_ + h * DH_ + kcol,
                          &Ks[t * 8 + i * 2048]);
                gld_lds16(vT + ((size_t)bh * DH_ + i * 32 + vrow) * L_ + kv0 + vcol,
                          &Vs[t * 8 + i * 2048]);
            }
            __syncthreads();

            f32x4_t sacc[4];
#pragma unroll
            for (int j = 0; j < 4; j++) sacc[j] = (f32x4_t){0.f, 0.f, 0.f, 0.f};
#pragma unroll
            for (int j = 0; j < 4; j++)
#pragma unroll
                for (int kk = 0; kk < 4; kk++) {
                    bf16x8_t bk_ = *(const bf16x8_t*)
                        &Ks[(j * 16 + l16) * 128 + (((kk * 4 + quad) ^ l16) << 3)];
                    sacc[j] = __builtin_amdgcn_mfma_f32_16x16x32_bf16(aq[kk], bk_, sacc[j], 0, 0, 0);
                }

            if (kt == qt) {
                const int qbase = qt * 64 + wave * 16 + quad * 4;
#pragma unroll
                for (int j = 0; j < 4; j++) {
                    const int key = kv0 + j * 16 + l16;
#pragma unroll
                    for (int r = 0; r < 4; r++)
                        if (key > qbase + r) sacc[j][r] = -1e30f;
                }
            }

            float alpha[4];
#pragma unroll
            for (int r = 0; r < 4; r++) {
                float mx = fmaxf(fmaxf(sacc[0][r], sacc[1][r]), fmaxf(sacc[2][r], sacc[3][r]));
#pragma unroll
                for (int off = 1; off < 16; off <<= 1) mx = fmaxf(mx, __shfl_xor(mx, off));
                const float mnew = fmaxf(mrow[r], mx);
                alpha[r] = exp2f(mrow[r] - mnew);
                float s0 = 0.f;
#pragma unroll
                for (int j = 0; j < 4; j++) {
                    const float pv = exp2f(sacc[j][r] - mnew);
                    Ps[wave][(quad * 4 + r) * 72 + j * 16 + l16] = __float2bfloat16(pv);
                    s0 += pv;
                }
#pragma unroll
                for (int off = 1; off < 16; off <<= 1) s0 += __shfl_xor(s0, off);
                lrow[r] = lrow[r] * alpha[r] + s0;
                mrow[r] = mnew;
            }

#pragma unroll
            for (int jj = 0; jj < 8; jj++)
#pragma unroll
                for (int r = 0; r < 4; r++) oacc[jj][r] *= alpha[r];

#pragma unroll
            for (int kk2 = 0; kk2 < 2; kk2++) {
                bf16x8_t ap = *(const bf16x8_t*)&Ps[wave][l16 * 72 + kk2 * 32 + quad * 8];
#pragma unroll
                for (int jj = 0; jj < 8; jj++) {
                    bf16x8_t bv_ = *(const bf16x8_t*)
                        &Vs[(jj * 16 + l16) * 64 + (((kk2 * 4 + quad) ^ (l16 & 7)) << 3)];
                    oacc[jj] = __builtin_amdgcn_mfma_f32_16x16x32_bf16(ap, bv_, oacc[jj], 0, 0, 0);
                }
            }
        }

#pragma unroll
        for (int r = 0; r < 4; r++) {
            const int qi = qt * 64 + wave * 16 + quad * 4 + r;
            const float inv = 1.0f / lrow[r];
#pragma unroll
            for (int jj = 0; jj < 8; jj++) {
                const int d = jj * 16 + l16;
                o[(size_t)(b * L_ + qi) * INNER_ + h * DH_ + d] =
                    __float2bfloat16(oacc[jj][r] * inv);
            }
        }
    }
}

// ---------------------------------------------------------------- launch
extern "C" void kernel_launch(void* const* d_in, const int* in_sizes, int n_in,
                              void* d_out, int out_size, void* d_ws, size_t ws_size,
                              hipStream_t stream) {
    const float* x      = (const float*)d_in[0];
    const float* pe_cos = (const float*)d_in[1];
    const float* pe_sin = (const float*)d_in[2];
    const float* lls    = (const float*)d_in[3];
    const float* wq     = (const float*)d_in[4];
    const float* bq     = (const float*)d_in[5];
    const float* wk     = (const float*)d_in[6];
    const float* bk     = (const float*)d_in[7];
    const float* wv     = (const float*)d_in[8];
    const float* bv     = (const float*)d_in[9];
    const float* qn     = (const float*)d_in[10];
    const float* kn     = (const float*)d_in[11];
    const float* wo     = (const float*)d_in[12];
    const float* bo     = (const float*)d_in[13];

    char* ws = (char*)d_ws;
    const size_t SZ_W = (size_t)D_ * INNER_ * 2;   // 8 MB (bf16)
    const size_t SZ_M = (size_t)M_ * INNER_ * 2;   // 16 MB (bf16)
    __hip_bfloat16* xb     = (__hip_bfloat16*)ws;  ws += SZ_M;
    __hip_bfloat16* wqkvT  = (__hip_bfloat16*)ws;  ws += 3 * SZ_W;  // [6144][2048]
    __hip_bfloat16* woT    = (__hip_bfloat16*)ws;  ws += SZ_W;
    __hip_bfloat16* qb     = (__hip_bfloat16*)ws;  ws += SZ_M;
    __hip_bfloat16* kb     = (__hip_bfloat16*)ws;  ws += SZ_M;
    __hip_bfloat16* vb     = (__hip_bfloat16*)ws;  ws += SZ_M;
    __hip_bfloat16* vT     = (__hip_bfloat16*)ws;  ws += SZ_M;
    __hip_bfloat16* ab     = (__hip_bfloat16*)ws;  ws += SZ_M;
    (void)in_sizes; (void)n_in; (void)out_size; (void)ws_size;

    const dim3 tb(256);
    const dim3 gT(64, 64);

    // 0. cast x to bf16
    k_cast<<<(M_ * D_) / 1024, tb, 0, stream>>>(x, (unsigned short*)xb);

    // 1. transpose+cast weights to bf16 [N][K]; q/k/v into one contiguous buffer
    k_transpose_cast<<<gT, tb, 0, stream>>>(wq, (unsigned short*)(wqkvT));
    k_transpose_cast<<<gT, tb, 0, stream>>>(wk, (unsigned short*)(wqkvT + (size_t)INNER_ * D_));
    k_transpose_cast<<<gT, tb, 0, stream>>>(wv, (unsigned short*)(wqkvT + 2 * (size_t)INNER_ * D_));
    k_transpose_cast<<<gT, tb, 0, stream>>>(wo, (unsigned short*)woT);

    // 2. fused QKV projection (1536 blocks = 6/CU)
    k_gemm_qkv<<<dim3(M_ / 128, 48), tb, 0, stream>>>(xb, wqkvT, bq, bk, bv, qb, kb, vb);

    // 3. RMSNorm + RoPE (+ fold softmax scale, logit scale, log2e into q)
    const float qextra = 0.08838834764831843f /* rsqrt(128) */ * 1.4426950408889634f /* log2 e */;
    k_rmsrope<<<M_, tb, 0, stream>>>(qb, qn, pe_cos, pe_sin, lls, qextra);
    k_rmsrope<<<M_, tb, 0, stream>>>(kb, kn, pe_cos, pe_sin, nullptr, 1.0f);

    // 4. transpose v per batch
    k_transpose2048<<<gT, tb, 0, stream>>>((const unsigned short*)vb, (unsigned short*)vT);
    k_transpose2048<<<gT, tb, 0, stream>>>((const unsigned short*)(vb + (size_t)L_ * INNER_),
                                           (unsigned short*)(vT + (size_t)L_ * INNER_));

    // 5. causal flash attention (paired q-tiles, swizzled LDS)
    k_attn<<<dim3(16, B_ * H_), tb, 0, stream>>>(qb, kb, vT, ab);

    // 6. output projection -> d_out (f32)
    k_gemm_bt_f32<<<dim3(M_ / 128, D_ / 128), tb, 0, stream>>>(ab, woT, bo, (float*)d_out, M_, D_, INNER_);
}

// Round 4
// 458.747 us; speedup vs baseline: 1.5246x; 1.0383x over previous
//
#include <hip/hip_runtime.h>
#include <hip/hip_bf16.h>

typedef __bf16 bf16x8_t __attribute__((ext_vector_type(8)));
typedef float  f32x4_t  __attribute__((ext_vector_type(4)));

#define B_     2
#define L_     2048
#define D_     2048
#define H_     16
#define DH_    128
#define INNER_ 2048
#define M_     (B_ * L_)

// async global->LDS, 16B per lane. LDS dest must be wave-uniform base + lane*16.
__device__ __forceinline__ void gld_lds16(const void* g, void* l) {
    __builtin_amdgcn_global_load_lds(
        (const __attribute__((address_space(1))) void*)g,
        (__attribute__((address_space(3))) void*)l,
        16, 0, 0);
}

__device__ __forceinline__ unsigned short f2bf(float f) {
    __hip_bfloat16 h = __float2bfloat16(f);
    return *(unsigned short*)&h;
}
__device__ __forceinline__ float bf2f(unsigned short s) {
    return __uint_as_float(((unsigned)s) << 16);
}

// ---------------------------------------------------------------- cast f32 -> bf16
__global__ __launch_bounds__(256)
void k_cast(const float* __restrict__ in, unsigned short* __restrict__ out) {
    const size_t i = ((size_t)blockIdx.x * 256 + threadIdx.x) * 4;
    float4 v = *(const float4*)(in + i);
    ushort4 o;
    o.x = f2bf(v.x); o.y = f2bf(v.y); o.z = f2bf(v.z); o.w = f2bf(v.w);
    *(ushort4*)(out + i) = o;
}

// ---------------------------------------------------------------- transpose+cast
__global__ __launch_bounds__(256)
void k_transpose_cast(const float* __restrict__ in, unsigned short* __restrict__ out) {
    __shared__ unsigned short tile[32][33];
    const int t  = threadIdx.x;
    const int r  = t >> 3;
    const int c4 = (t & 7) << 2;
    const size_t ib = ((size_t)blockIdx.y * 32 + r) * 2048 + blockIdx.x * 32 + c4;
    float4 v = *(const float4*)(in + ib);
    tile[r][c4 + 0] = f2bf(v.x); tile[r][c4 + 1] = f2bf(v.y);
    tile[r][c4 + 2] = f2bf(v.z); tile[r][c4 + 3] = f2bf(v.w);
    __syncthreads();
    ushort4 o;
    o.x = tile[c4 + 0][r]; o.y = tile[c4 + 1][r];
    o.z = tile[c4 + 2][r]; o.w = tile[c4 + 3][r];
    const size_t ob = ((size_t)blockIdx.x * 32 + r) * 2048 + blockIdx.y * 32 + c4;
    *(ushort4*)(out + ob) = o;
}

// ---------------------------------------------------------------- transpose (bf16)
__global__ __launch_bounds__(256)
void k_transpose2048(const unsigned short* __restrict__ in,
                     unsigned short* __restrict__ out) {
    __shared__ unsigned short tile[32][33];
    const int t  = threadIdx.x;
    const int r  = t >> 3;
    const int c4 = (t & 7) << 2;
    const size_t ib = ((size_t)blockIdx.y * 32 + r) * 2048 + blockIdx.x * 32 + c4;
    ushort4 v = *(const ushort4*)(in + ib);
    tile[r][c4 + 0] = v.x; tile[r][c4 + 1] = v.y;
    tile[r][c4 + 2] = v.z; tile[r][c4 + 3] = v.w;
    __syncthreads();
    ushort4 o;
    o.x = tile[c4 + 0][r]; o.y = tile[c4 + 1][r];
    o.z = tile[c4 + 2][r]; o.w = tile[c4 + 3][r];
    const size_t ob = ((size_t)blockIdx.x * 32 + r) * 2048 + blockIdx.y * 32 + c4;
    *(ushort4*)(out + ob) = o;
}

// ---------------------------------------------------------------- GEMM core macro body
#define GEMM_BODY(A_, Bt_, K_)                                                 \
    __shared__ __align__(16) __hip_bfloat16 As[128 * 32];                      \
    __shared__ __align__(16) __hip_bfloat16 Bs[128 * 32];                      \
    const int t    = threadIdx.x;                                              \
    const int lane = t & 63;                                                   \
    const int wave = t >> 6;                                                   \
    const int quad = lane >> 4;                                                \
    const int l16  = lane & 15;                                                \
    const int wm   = (wave >> 1) * 64;                                         \
    const int wn   = (wave & 1) * 64;                                          \
    const int srow = t >> 2;                                                   \
    const int scol = (t & 3) << 3;                                             \
    const __hip_bfloat16* Ag = A_  + (size_t)(tileM + srow) * K_ + scol;       \
    const __hip_bfloat16* Bg = Bt_ + (size_t)(tileN + srow) * K_ + scol;       \
    __hip_bfloat16* Asl  = &As[t * 8];                                         \
    __hip_bfloat16* Asl2 = &As[2048 + t * 8];                                  \
    __hip_bfloat16* Bsl  = &Bs[t * 8];                                         \
    __hip_bfloat16* Bsl2 = &Bs[2048 + t * 8];                                  \
    const size_t rowskip = (size_t)64 * K_;                                    \
    f32x4_t acc[4][4];                                                         \
    _Pragma("unroll") for (int i = 0; i < 4; i++)                              \
        _Pragma("unroll") for (int j = 0; j < 4; j++)                          \
            acc[i][j] = (f32x4_t){0.f, 0.f, 0.f, 0.f};                         \
    for (int k0 = 0; k0 < K_; k0 += 32) {                                      \
        __syncthreads();                                                       \
        gld_lds16(Ag + k0,           Asl);                                     \
        gld_lds16(Ag + rowskip + k0, Asl2);                                    \
        gld_lds16(Bg + k0,           Bsl);                                     \
        gld_lds16(Bg + rowskip + k0, Bsl2);                                    \
        __syncthreads();                                                       \
        bf16x8_t af[4], bfr[4];                                                \
        _Pragma("unroll") for (int i = 0; i < 4; i++)                          \
            af[i] = *(const bf16x8_t*)&As[(wm + i * 16 + l16) * 32 + quad * 8];\
        _Pragma("unroll") for (int j = 0; j < 4; j++)                          \
            bfr[j] = *(const bf16x8_t*)&Bs[(wn + j * 16 + l16) * 32 + quad * 8];\
        _Pragma("unroll") for (int i = 0; i < 4; i++)                          \
            _Pragma("unroll") for (int j = 0; j < 4; j++)                      \
                acc[i][j] = __builtin_amdgcn_mfma_f32_16x16x32_bf16(           \
                    af[i], bfr[j], acc[i][j], 0, 0, 0);                        \
    }

// wo GEMM: f32 output to d_out
__global__ __launch_bounds__(256)
void k_gemm_bt_f32(const __hip_bfloat16* __restrict__ A,
                   const __hip_bfloat16* __restrict__ Bt,
                   const float* __restrict__ bias,
                   float* __restrict__ C,
                   int M, int N, int K) {
    const int tileM = blockIdx.x * 128;
    const int tileN = blockIdx.y * 128;
    GEMM_BODY(A, Bt, K)
#pragma unroll
    for (int i = 0; i < 4; i++)
#pragma unroll
        for (int r = 0; r < 4; r++) {
            const int m = tileM + wm + i * 16 + quad * 4 + r;
#pragma unroll
            for (int j = 0; j < 4; j++) {
                const int n = tileN + wn + j * 16 + l16;
                C[(size_t)m * N + n] = acc[i][j][r] + bias[n];
            }
        }
}

// fused QKV GEMM: Bt is [3*INNER][D] (wq^T|wk^T|wv^T), grid.y = 48.
__global__ __launch_bounds__(256)
void k_gemm_qkv(const __hip_bfloat16* __restrict__ A,
                const __hip_bfloat16* __restrict__ Bt,
                const float* __restrict__ bq, const float* __restrict__ bk,
                const float* __restrict__ bv,
                __hip_bfloat16* __restrict__ qo, __hip_bfloat16* __restrict__ ko,
                __hip_bfloat16* __restrict__ vo) {
    const int tileM = blockIdx.x * 128;
    const int tileN = blockIdx.y * 128;
    GEMM_BODY(A, Bt, D_)
    const int sel  = blockIdx.y >> 4;
    const int nbas = tileN - sel * INNER_;
    const float* bias = (sel == 0) ? bq : (sel == 1) ? bk : bv;
    __hip_bfloat16* C = (sel == 0) ? qo : (sel == 1) ? ko : vo;
#pragma unroll
    for (int i = 0; i < 4; i++)
#pragma unroll
        for (int r = 0; r < 4; r++) {
            const int m = tileM + wm + i * 16 + quad * 4 + r;
#pragma unroll
            for (int j = 0; j < 4; j++) {
                const int n = nbas + wn + j * 16 + l16;
                C[(size_t)m * INNER_ + n] = __float2bfloat16(acc[i][j][r] + bias[n]);
            }
        }
}

// ---------------------------------------------------------------- RMSNorm + RoPE
__global__ __launch_bounds__(256)
void k_rmsrope(__hip_bfloat16* __restrict__ buf,
               const float* __restrict__ w,
               const float* __restrict__ pcos,
               const float* __restrict__ psin,
               const float* __restrict__ lls,
               float extra) {
    const int row = blockIdx.x;
    const int l   = row & (L_ - 1);
    const int t   = threadIdx.x;
    __hip_bfloat16* p = buf + (size_t)row * INNER_ + t * 8;

    float x[8];
    {
        const unsigned short* ps = (const unsigned short*)p;
        ushort4 a = *(const ushort4*)ps;
        ushort4 b = *(const ushort4*)(ps + 4);
        unsigned short s[8] = {a.x, a.y, a.z, a.w, b.x, b.y, b.z, b.w};
#pragma unroll
        for (int i = 0; i < 8; i++) x[i] = bf2f(s[i]);
    }
    float ss = 0.f;
#pragma unroll
    for (int i = 0; i < 8; i++) ss += x[i] * x[i];
#pragma unroll
    for (int off = 32; off >= 1; off >>= 1) ss += __shfl_down(ss, off);
    __shared__ float red[4];
    if ((t & 63) == 0) red[t >> 6] = ss;
    __syncthreads();
    ss = red[0] + red[1] + red[2] + red[3];
    const float rstd = rsqrtf(ss * (1.0f / (float)INNER_) + 1e-6f);

    float scale = extra;
    if (lls) scale *= lls[l];

    const float4 c4 = ((const float4*)(pcos + (size_t)l * (INNER_ / 2)))[t];
    const float4 s4 = ((const float4*)(psin + (size_t)l * (INNER_ / 2)))[t];
    const float cc[4] = {c4.x, c4.y, c4.z, c4.w};
    const float sn[4] = {s4.x, s4.y, s4.z, s4.w};
    const float4 w0 = ((const float4*)w)[t * 2];
    const float4 w1 = ((const float4*)w)[t * 2 + 1];
    const float ww[8] = {w0.x, w0.y, w0.z, w0.w, w1.x, w1.y, w1.z, w1.w};

    union { __hip_bfloat16 h[8]; uint4 u; } pk;
#pragma unroll
    for (int pi = 0; pi < 4; pi++) {
        const float y1 = x[pi * 2]     * rstd * ww[pi * 2];
        const float y2 = x[pi * 2 + 1] * rstd * ww[pi * 2 + 1];
        pk.h[pi * 2]     = __float2bfloat16((y1 * cc[pi] - y2 * sn[pi]) * scale);
        pk.h[pi * 2 + 1] = __float2bfloat16((y1 * sn[pi] + y2 * cc[pi]) * scale);
    }
    *(uint4*)p = pk.u;
}

// ---------------------------------------------------------------- attention
// Causal flash attention, S^T formulation.
// S^T = K·Q^T (A=K frag, B=Q frag — identical fragment layouts), so the C
// layout has q-row on l16 and key on (quad,reg): softmax is lane-local + 2
// shfl_xor; P^T writes are packed ds_write_b64; PV is O^T = V^T·P^T with
// A=V^T straight from Vs[d][key]. Each wave owns 32 q-rows (2 sets of 16) so
// Ks/Vs fragments are reused 2x. Block = 4 waves = 128 q-rows; grid (8, B*H)
// with q-tile pairing (p, 15-p) -> uniform 34 key-tile iterations per block.
__global__ __launch_bounds__(256)
void k_attn(const __hip_bfloat16* __restrict__ q,
            const __hip_bfloat16* __restrict__ k,
            const __hip_bfloat16* __restrict__ vT,
            __hip_bfloat16* __restrict__ o) {
    __shared__ __align__(16) __hip_bfloat16 Ks[64 * 128];   // [key][d] swizzled
    __shared__ __align__(16) __hip_bfloat16 Vs[128 * 64];   // [d][key] swizzled
    __shared__ __align__(16) __hip_bfloat16 Pt[8][16 * 72]; // [wave*2+s][qrow][key] stride 72

    const int p  = blockIdx.x;   // 0..7
    const int bh = blockIdx.y;
    const int b  = bh >> 4;
    const int h  = bh & 15;
    const int t = threadIdx.x, wave = t >> 6, lane = t & 63;
    const int quad = lane >> 4, l16 = lane & 15;

    const int krow = t >> 4, kcol = ((t & 15) ^ krow) << 3;
    const int vrow = t >> 3, vcol = ((t & 7) ^ (vrow & 7)) << 3;

    for (int half = 0; half < 2; ++half) {
        const int qt = half ? (15 - p) : p;
        const int rowbase = qt * 128 + wave * 32;

        bf16x8_t aq[2][4];
#pragma unroll
        for (int s = 0; s < 2; s++) {
            const size_t qoff = (size_t)(b * L_ + rowbase + s * 16 + l16) * INNER_ + h * DH_;
#pragma unroll
            for (int kk = 0; kk < 4; kk++)
                aq[s][kk] = *(const bf16x8_t*)(q + qoff + kk * 32 + quad * 8);
        }

        f32x4_t oacc[2][8];
#pragma unroll
        for (int s = 0; s < 2; s++)
#pragma unroll
            for (int jj = 0; jj < 8; jj++) oacc[s][jj] = (f32x4_t){0.f, 0.f, 0.f, 0.f};
        float m_[2] = {-1e30f, -1e30f};
        float l_[2] = {0.f, 0.f};

        const int nkt = 2 * qt + 2;
        for (int kt = 0; kt < nkt; ++kt) {
            const int kv0 = kt * 64;
            __syncthreads();
#pragma unroll
            for (int i = 0; i < 4; i++) {
                gld_lds16(k  + (size_t)(b * L_ + kv0 + i * 16 + krow) * INNER_ + h * DH_ + kcol,
                          &Ks[t * 8 + i * 2048]);
                gld_lds16(vT + ((size_t)bh * DH_ + i * 32 + vrow) * L_ + kv0 + vcol,
                          &Vs[t * 8 + i * 2048]);
            }
            __syncthreads();

            if (kv0 > rowbase + 31) continue;   // this wave's rows all precede kv0

            // S^T = K . Q^T : per set, 4 key-tiles of 16
            f32x4_t sacc[2][4];
#pragma unroll
            for (int s = 0; s < 2; s++)
#pragma unroll
                for (int tt = 0; tt < 4; tt++) sacc[s][tt] = (f32x4_t){0.f, 0.f, 0.f, 0.f};
#pragma unroll
            for (int kk = 0; kk < 4; kk++) {
                bf16x8_t kf[4];
#pragma unroll
                for (int tt = 0; tt < 4; tt++)
                    kf[tt] = *(const bf16x8_t*)&Ks[(tt * 16 + l16) * 128 + (((kk * 4 + quad) ^ l16) << 3)];
#pragma unroll
                for (int s = 0; s < 2; s++)
#pragma unroll
                    for (int tt = 0; tt < 4; tt++)
                        sacc[s][tt] = __builtin_amdgcn_mfma_f32_16x16x32_bf16(
                            kf[tt], aq[s][kk], sacc[s][tt], 0, 0, 0);
            }

            const bool diag = (kv0 + 63 > rowbase);
#pragma unroll
            for (int s = 0; s < 2; s++) {
                const int sbase = rowbase + s * 16;
                if (diag) {
                    const int qrow = sbase + l16;
#pragma unroll
                    for (int tt = 0; tt < 4; tt++)
#pragma unroll
                        for (int r = 0; r < 4; r++)
                            if (kv0 + tt * 16 + quad * 4 + r > qrow) sacc[s][tt][r] = -1e30f;
                }
                // row max: lane-local 16 + 2 shfl
                float mx = sacc[s][0][0];
#pragma unroll
                for (int tt = 0; tt < 4; tt++)
#pragma unroll
                    for (int r = 0; r < 4; r++) mx = fmaxf(mx, sacc[s][tt][r]);
                mx = fmaxf(mx, __shfl_xor(mx, 16));
                mx = fmaxf(mx, __shfl_xor(mx, 32));
                const float mnew = fmaxf(m_[s], mx);
                const float alpha = exp2f(m_[s] - mnew);
                m_[s] = mnew;

                float ls = 0.f;
#pragma unroll
                for (int tt = 0; tt < 4; tt++) {
                    ushort4 pk;
                    float p0 = exp2f(sacc[s][tt][0] - mnew);
                    float p1 = exp2f(sacc[s][tt][1] - mnew);
                    float p2 = exp2f(sacc[s][tt][2] - mnew);
                    float p3 = exp2f(sacc[s][tt][3] - mnew);
                    ls += (p0 + p1) + (p2 + p3);
                    pk.x = f2bf(p0); pk.y = f2bf(p1); pk.z = f2bf(p2); pk.w = f2bf(p3);
                    *(ushort4*)&Pt[wave * 2 + s][l16 * 72 + tt * 16 + quad * 4] = pk;
                }
                ls += __shfl_xor(ls, 16);
                ls += __shfl_xor(ls, 32);
                l_[s] = l_[s] * alpha + ls;
#pragma unroll
                for (int jj = 0; jj < 8; jj++) {
                    oacc[s][jj][0] *= alpha; oacc[s][jj][1] *= alpha;
                    oacc[s][jj][2] *= alpha; oacc[s][jj][3] *= alpha;
                }
            }

            // O^T += V^T . P^T  (Vs fragments shared across both sets)
#pragma unroll
            for (int kk2 = 0; kk2 < 2; kk2++) {
                bf16x8_t pf0 = *(const bf16x8_t*)&Pt[wave * 2 + 0][l16 * 72 + kk2 * 32 + quad * 8];
                bf16x8_t pf1 = *(const bf16x8_t*)&Pt[wave * 2 + 1][l16 * 72 + kk2 * 32 + quad * 8];
#pragma unroll
                for (int jj = 0; jj < 8; jj++) {
                    bf16x8_t vf = *(const bf16x8_t*)
                        &Vs[(jj * 16 + l16) * 64 + (((kk2 * 4 + quad) ^ (l16 & 7)) << 3)];
                    oacc[0][jj] = __builtin_amdgcn_mfma_f32_16x16x32_bf16(vf, pf0, oacc[0][jj], 0, 0, 0);
                    oacc[1][jj] = __builtin_amdgcn_mfma_f32_16x16x32_bf16(vf, pf1, oacc[1][jj], 0, 0, 0);
                }
            }
        }

        // epilogue: O^T C-layout -> o[q][h*128+d]; d = jj*16 + quad*4 + r
#pragma unroll
        for (int s = 0; s < 2; s++) {
            const float inv = 1.0f / l_[s];
            __hip_bfloat16* orow = o + (size_t)(b * L_ + rowbase + s * 16 + l16) * INNER_ + h * DH_;
#pragma unroll
            for (int jj = 0; jj < 8; jj++) {
                ushort4 pk;
                pk.x = f2bf(oacc[s][jj][0] * inv);
                pk.y = f2bf(oacc[s][jj][1] * inv);
                pk.z = f2bf(oacc[s][jj][2] * inv);
                pk.w = f2bf(oacc[s][jj][3] * inv);
                *(ushort4*)(orow + jj * 16 + quad * 4) = pk;
            }
        }
    }
}

// ---------------------------------------------------------------- launch
extern "C" void kernel_launch(void* const* d_in, const int* in_sizes, int n_in,
                              void* d_out, int out_size, void* d_ws, size_t ws_size,
                              hipStream_t stream) {
    const float* x      = (const float*)d_in[0];
    const float* pe_cos = (const float*)d_in[1];
    const float* pe_sin = (const float*)d_in[2];
    const float* lls    = (const float*)d_in[3];
    const float* wq     = (const float*)d_in[4];
    const float* bq     = (const float*)d_in[5];
    const float* wk     = (const float*)d_in[6];
    const float* bk     = (const float*)d_in[7];
    const float* wv     = (const float*)d_in[8];
    const float* bv     = (const float*)d_in[9];
    const float* qn     = (const float*)d_in[10];
    const float* kn     = (const float*)d_in[11];
    const float* wo     = (const float*)d_in[12];
    const float* bo     = (const float*)d_in[13];

    char* ws = (char*)d_ws;
    const size_t SZ_W = (size_t)D_ * INNER_ * 2;   // 8 MB (bf16)
    const size_t SZ_M = (size_t)M_ * INNER_ * 2;   // 16 MB (bf16)
    __hip_bfloat16* xb     = (__hip_bfloat16*)ws;  ws += SZ_M;
    __hip_bfloat16* wqkvT  = (__hip_bfloat16*)ws;  ws += 3 * SZ_W;  // [6144][2048]
    __hip_bfloat16* woT    = (__hip_bfloat16*)ws;  ws += SZ_W;
    __hip_bfloat16* qb     = (__hip_bfloat16*)ws;  ws += SZ_M;
    __hip_bfloat16* kb     = (__hip_bfloat16*)ws;  ws += SZ_M;
    __hip_bfloat16* vb     = (__hip_bfloat16*)ws;  ws += SZ_M;
    __hip_bfloat16* vT     = (__hip_bfloat16*)ws;  ws += SZ_M;
    __hip_bfloat16* ab     = (__hip_bfloat16*)ws;  ws += SZ_M;
    (void)in_sizes; (void)n_in; (void)out_size; (void)ws_size;

    const dim3 tb(256);
    const dim3 gT(64, 64);

    // 0. cast x to bf16
    k_cast<<<(M_ * D_) / 1024, tb, 0, stream>>>(x, (unsigned short*)xb);

    // 1. transpose+cast weights to bf16 [N][K]; q/k/v into one contiguous buffer
    k_transpose_cast<<<gT, tb, 0, stream>>>(wq, (unsigned short*)(wqkvT));
    k_transpose_cast<<<gT, tb, 0, stream>>>(wk, (unsigned short*)(wqkvT + (size_t)INNER_ * D_));
    k_transpose_cast<<<gT, tb, 0, stream>>>(wv, (unsigned short*)(wqkvT + 2 * (size_t)INNER_ * D_));
    k_transpose_cast<<<gT, tb, 0, stream>>>(wo, (unsigned short*)woT);

    // 2. fused QKV projection
    k_gemm_qkv<<<dim3(M_ / 128, 48), tb, 0, stream>>>(xb, wqkvT, bq, bk, bv, qb, kb, vb);

    // 3. RMSNorm + RoPE (+ fold softmax scale, logit scale, log2e into q)
    const float qextra = 0.08838834764831843f /* rsqrt(128) */ * 1.4426950408889634f /* log2 e */;
    k_rmsrope<<<M_, tb, 0, stream>>>(qb, qn, pe_cos, pe_sin, lls, qextra);
    k_rmsrope<<<M_, tb, 0, stream>>>(kb, kn, pe_cos, pe_sin, nullptr, 1.0f);

    // 4. transpose v per batch
    k_transpose2048<<<gT, tb, 0, stream>>>((const unsigned short*)vb, (unsigned short*)vT);
    k_transpose2048<<<gT, tb, 0, stream>>>((const unsigned short*)(vb + (size_t)L_ * INNER_),
                                           (unsigned short*)(vT + (size_t)L_ * INNER_));

    // 5. causal flash attention (S^T formulation, 128-row q-tiles, paired)
    k_attn<<<dim3(8, B_ * H_), tb, 0, stream>>>(qb, kb, vT, ab);

    // 6. output projection -> d_out (f32)
    k_gemm_bt_f32<<<dim3(M_ / 128, D_ / 128), tb, 0, stream>>>(ab, woT, bo, (float*)d_out, M_, D_, INNER_);
}

// Round 5
// 446.925 us; speedup vs baseline: 1.5649x; 1.0265x over previous
//
#include <hip/hip_runtime.h>
#include <hip/hip_bf16.h>

typedef __bf16 bf16x8_t __attribute__((ext_vector_type(8)));
typedef float  f32x4_t  __attribute__((ext_vector_type(4)));

#define B_     2
#define L_     2048
#define D_     2048
#define H_     16
#define DH_    128
#define INNER_ 2048
#define M_     (B_ * L_)

// async global->LDS, 16B per lane. LDS dest must be wave-uniform base + lane*16.
__device__ __forceinline__ void gld_lds16(const void* g, void* l) {
    __builtin_amdgcn_global_load_lds(
        (const __attribute__((address_space(1))) void*)g,
        (__attribute__((address_space(3))) void*)l,
        16, 0, 0);
}

__device__ __forceinline__ unsigned short f2bf(float f) {
    __hip_bfloat16 h = __float2bfloat16(f);
    return *(unsigned short*)&h;
}
__device__ __forceinline__ float bf2f(unsigned short s) {
    return __uint_as_float(((unsigned)s) << 16);
}

// ---------------------------------------------------------------- cast f32 -> bf16
__global__ __launch_bounds__(256)
void k_cast(const float* __restrict__ in, unsigned short* __restrict__ out) {
    const size_t i = ((size_t)blockIdx.x * 256 + threadIdx.x) * 4;
    float4 v = *(const float4*)(in + i);
    ushort4 o;
    o.x = f2bf(v.x); o.y = f2bf(v.y); o.z = f2bf(v.z); o.w = f2bf(v.w);
    *(ushort4*)(out + i) = o;
}

// ---------------------------------------------------------------- fused 4x transpose+cast
// z selects which weight; 2048x2048 f32 -> bf16 transposed.
__global__ __launch_bounds__(256)
void k_wtrans4(const float* __restrict__ w0, const float* __restrict__ w1,
               const float* __restrict__ w2, const float* __restrict__ w3,
               unsigned short* __restrict__ d0, unsigned short* __restrict__ d1,
               unsigned short* __restrict__ d2, unsigned short* __restrict__ d3) {
    const int z = blockIdx.z;
    const float* in = (z == 0) ? w0 : (z == 1) ? w1 : (z == 2) ? w2 : w3;
    unsigned short* out = (z == 0) ? d0 : (z == 1) ? d1 : (z == 2) ? d2 : d3;
    __shared__ unsigned short tile[32][33];
    const int t  = threadIdx.x;
    const int r  = t >> 3;
    const int c4 = (t & 7) << 2;
    const size_t ib = ((size_t)blockIdx.y * 32 + r) * 2048 + blockIdx.x * 32 + c4;
    float4 v = *(const float4*)(in + ib);
    tile[r][c4 + 0] = f2bf(v.x); tile[r][c4 + 1] = f2bf(v.y);
    tile[r][c4 + 2] = f2bf(v.z); tile[r][c4 + 3] = f2bf(v.w);
    __syncthreads();
    ushort4 o;
    o.x = tile[c4 + 0][r]; o.y = tile[c4 + 1][r];
    o.z = tile[c4 + 2][r]; o.w = tile[c4 + 3][r];
    const size_t ob = ((size_t)blockIdx.x * 32 + r) * 2048 + blockIdx.y * 32 + c4;
    *(ushort4*)(out + ob) = o;
}

// ---------------------------------------------------------------- GEMM core macro body
#define GEMM_BODY(A_, Bt_, K_)                                                 \
    __shared__ __align__(16) __hip_bfloat16 As[128 * 32];                      \
    __shared__ __align__(16) __hip_bfloat16 Bs[128 * 32];                      \
    const int t    = threadIdx.x;                                              \
    const int lane = t & 63;                                                   \
    const int wave = t >> 6;                                                   \
    const int quad = lane >> 4;                                                \
    const int l16  = lane & 15;                                                \
    const int wm   = (wave >> 1) * 64;                                         \
    const int wn   = (wave & 1) * 64;                                          \
    const int srow = t >> 2;                                                   \
    const int scol = (t & 3) << 3;                                             \
    const __hip_bfloat16* Ag = A_  + (size_t)(tileM + srow) * K_ + scol;       \
    const __hip_bfloat16* Bg = Bt_ + (size_t)(tileN + srow) * K_ + scol;       \
    __hip_bfloat16* Asl  = &As[t * 8];                                         \
    __hip_bfloat16* Asl2 = &As[2048 + t * 8];                                  \
    __hip_bfloat16* Bsl  = &Bs[t * 8];                                         \
    __hip_bfloat16* Bsl2 = &Bs[2048 + t * 8];                                  \
    const size_t rowskip = (size_t)64 * K_;                                    \
    f32x4_t acc[4][4];                                                         \
    _Pragma("unroll") for (int i = 0; i < 4; i++)                              \
        _Pragma("unroll") for (int j = 0; j < 4; j++)                          \
            acc[i][j] = (f32x4_t){0.f, 0.f, 0.f, 0.f};                         \
    for (int k0 = 0; k0 < K_; k0 += 32) {                                      \
        __syncthreads();                                                       \
        gld_lds16(Ag + k0,           Asl);                                     \
        gld_lds16(Ag + rowskip + k0, Asl2);                                    \
        gld_lds16(Bg + k0,           Bsl);                                     \
        gld_lds16(Bg + rowskip + k0, Bsl2);                                    \
        __syncthreads();                                                       \
        bf16x8_t af[4], bfr[4];                                                \
        _Pragma("unroll") for (int i = 0; i < 4; i++)                          \
            af[i] = *(const bf16x8_t*)&As[(wm + i * 16 + l16) * 32 + quad * 8];\
        _Pragma("unroll") for (int j = 0; j < 4; j++)                          \
            bfr[j] = *(const bf16x8_t*)&Bs[(wn + j * 16 + l16) * 32 + quad * 8];\
        _Pragma("unroll") for (int i = 0; i < 4; i++)                          \
            _Pragma("unroll") for (int j = 0; j < 4; j++)                      \
                acc[i][j] = __builtin_amdgcn_mfma_f32_16x16x32_bf16(           \
                    af[i], bfr[j], acc[i][j], 0, 0, 0);                        \
    }

// wo GEMM: f32 output to d_out
__global__ __launch_bounds__(256)
void k_gemm_bt_f32(const __hip_bfloat16* __restrict__ A,
                   const __hip_bfloat16* __restrict__ Bt,
                   const float* __restrict__ bias,
                   float* __restrict__ C,
                   int M, int N, int K) {
    const int tileM = blockIdx.x * 128;
    const int tileN = blockIdx.y * 128;
    GEMM_BODY(A, Bt, K)
#pragma unroll
    for (int i = 0; i < 4; i++)
#pragma unroll
        for (int r = 0; r < 4; r++) {
            const int m = tileM + wm + i * 16 + quad * 4 + r;
#pragma unroll
            for (int j = 0; j < 4; j++) {
                const int n = tileN + wn + j * 16 + l16;
                C[(size_t)m * N + n] = acc[i][j][r] + bias[n];
            }
        }
}

// fused QKV GEMM: Bt is [3*INNER][D] (wq^T|wk^T|wv^T), grid.y = 48.
// sel 0/1 -> q/k row-major; sel 2 -> v written directly transposed into
// vT[(b*H+h)*DH + d][l] (4 consecutive-m acc regs = 4 consecutive l -> ushort4).
__global__ __launch_bounds__(256)
void k_gemm_qkv(const __hip_bfloat16* __restrict__ A,
                const __hip_bfloat16* __restrict__ Bt,
                const float* __restrict__ bq, const float* __restrict__ bk,
                const float* __restrict__ bv,
                __hip_bfloat16* __restrict__ qo, __hip_bfloat16* __restrict__ ko,
                __hip_bfloat16* __restrict__ vTo) {
    const int tileM = blockIdx.x * 128;
    const int tileN = blockIdx.y * 128;
    GEMM_BODY(A, Bt, D_)
    const int sel  = blockIdx.y >> 4;
    const int nbas = tileN - sel * INNER_;
    if (sel < 2) {
        const float* bias = (sel == 0) ? bq : bk;
        __hip_bfloat16* C = (sel == 0) ? qo : ko;
#pragma unroll
        for (int i = 0; i < 4; i++)
#pragma unroll
            for (int r = 0; r < 4; r++) {
                const int m = tileM + wm + i * 16 + quad * 4 + r;
#pragma unroll
                for (int j = 0; j < 4; j++) {
                    const int n = nbas + wn + j * 16 + l16;
                    C[(size_t)m * INNER_ + n] = __float2bfloat16(acc[i][j][r] + bias[n]);
                }
            }
    } else {
        const int bb = tileM >> 11;   // batch (128-row tile never straddles)
#pragma unroll
        for (int i = 0; i < 4; i++) {
            const int l0 = (tileM + wm + i * 16 + quad * 4) & (L_ - 1);
#pragma unroll
            for (int j = 0; j < 4; j++) {
                const int n  = nbas + wn + j * 16 + l16;
                const int hh = n >> 7, dd = n & 127;
                const float bvn = bv[n];
                ushort4 pk;
                pk.x = f2bf(acc[i][j][0] + bvn);
                pk.y = f2bf(acc[i][j][1] + bvn);
                pk.z = f2bf(acc[i][j][2] + bvn);
                pk.w = f2bf(acc[i][j][3] + bvn);
                *(ushort4*)(vTo + ((size_t)(bb * H_ + hh) * DH_ + dd) * L_ + l0) = pk;
            }
        }
    }
}

// ---------------------------------------------------------------- RMSNorm + RoPE (q&k fused)
// grid (M, 2): y=0 -> q (with logit scale + softmax scale folded), y=1 -> k.
__global__ __launch_bounds__(256)
void k_rmsrope2(__hip_bfloat16* __restrict__ qb, __hip_bfloat16* __restrict__ kb,
                const float* __restrict__ qn, const float* __restrict__ kn,
                const float* __restrict__ pcos, const float* __restrict__ psin,
                const float* __restrict__ lls, float qextra) {
    const int which = blockIdx.y;
    __hip_bfloat16* buf = which ? kb : qb;
    const float* w = which ? kn : qn;
    const int row = blockIdx.x;
    const int l   = row & (L_ - 1);
    const int t   = threadIdx.x;
    __hip_bfloat16* p = buf + (size_t)row * INNER_ + t * 8;

    float x[8];
    {
        const unsigned short* ps = (const unsigned short*)p;
        ushort4 a = *(const ushort4*)ps;
        ushort4 b = *(const ushort4*)(ps + 4);
        unsigned short s[8] = {a.x, a.y, a.z, a.w, b.x, b.y, b.z, b.w};
#pragma unroll
        for (int i = 0; i < 8; i++) x[i] = bf2f(s[i]);
    }
    float ss = 0.f;
#pragma unroll
    for (int i = 0; i < 8; i++) ss += x[i] * x[i];
#pragma unroll
    for (int off = 32; off >= 1; off >>= 1) ss += __shfl_down(ss, off);
    __shared__ float red[4];
    if ((t & 63) == 0) red[t >> 6] = ss;
    __syncthreads();
    ss = red[0] + red[1] + red[2] + red[3];
    const float rstd = rsqrtf(ss * (1.0f / (float)INNER_) + 1e-6f);

    const float scale = which ? 1.0f : (qextra * lls[l]);

    const float4 c4 = ((const float4*)(pcos + (size_t)l * (INNER_ / 2)))[t];
    const float4 s4 = ((const float4*)(psin + (size_t)l * (INNER_ / 2)))[t];
    const float cc[4] = {c4.x, c4.y, c4.z, c4.w};
    const float sn[4] = {s4.x, s4.y, s4.z, s4.w};
    const float4 w0 = ((const float4*)w)[t * 2];
    const float4 w1 = ((const float4*)w)[t * 2 + 1];
    const float ww[8] = {w0.x, w0.y, w0.z, w0.w, w1.x, w1.y, w1.z, w1.w};

    union { __hip_bfloat16 h[8]; uint4 u; } pk;
#pragma unroll
    for (int pi = 0; pi < 4; pi++) {
        const float y1 = x[pi * 2]     * rstd * ww[pi * 2];
        const float y2 = x[pi * 2 + 1] * rstd * ww[pi * 2 + 1];
        pk.h[pi * 2]     = __float2bfloat16((y1 * cc[pi] - y2 * sn[pi]) * scale);
        pk.h[pi * 2 + 1] = __float2bfloat16((y1 * sn[pi] + y2 * cc[pi]) * scale);
    }
    *(uint4*)p = pk.u;
}

// ---------------------------------------------------------------- attention
// Causal flash attention, S^T formulation, 512 threads = 8 waves x 16 q-rows
// (2 waves/SIMD even at 1 block/CU). Block = 128 q-rows; grid (8, B*H) with
// q-tile pairing (p, 15-p) -> uniform 34 key-tile iterations per block.
__global__ __launch_bounds__(512)
void k_attn(const __hip_bfloat16* __restrict__ q,
            const __hip_bfloat16* __restrict__ k,
            const __hip_bfloat16* __restrict__ vT,
            __hip_bfloat16* __restrict__ o) {
    __shared__ __align__(16) __hip_bfloat16 Ks[64 * 128];   // [key][d] swizzled
    __shared__ __align__(16) __hip_bfloat16 Vs[128 * 64];   // [d][key] swizzled
    __shared__ __align__(16) __hip_bfloat16 Pt[8][16 * 72]; // [wave][qrow][key] stride 72

    const int p  = blockIdx.x;   // 0..7
    const int bh = blockIdx.y;
    const int b  = bh >> 4;
    const int h  = bh & 15;
    const int t = threadIdx.x, wave = t >> 6, lane = t & 63;
    const int quad = lane >> 4, l16 = lane & 15;

    // staging maps (XOR chunk swizzle on the global side)
    const int kr = t >> 4;                          // 0..31
    const int kc = ((t & 15) ^ (kr & 15)) << 3;
    const int vr = t >> 3;                          // 0..63
    const int vc = ((t & 7) ^ (vr & 7)) << 3;
    const __hip_bfloat16* kbase = k  + (size_t)b * L_ * INNER_ + h * DH_;
    const __hip_bfloat16* vbase = vT + (size_t)bh * DH_ * L_;

    for (int half = 0; half < 2; ++half) {
        const int qt = half ? (15 - p) : p;
        const int rowbase = qt * 128 + wave * 16;

        bf16x8_t aq[4];
        {
            const size_t qoff = (size_t)(b * L_ + rowbase + l16) * INNER_ + h * DH_;
#pragma unroll
            for (int kk = 0; kk < 4; kk++)
                aq[kk] = *(const bf16x8_t*)(q + qoff + kk * 32 + quad * 8);
        }

        f32x4_t oacc[8];
#pragma unroll
        for (int jj = 0; jj < 8; jj++) oacc[jj] = (f32x4_t){0.f, 0.f, 0.f, 0.f};
        float m_ = -1e30f, l_ = 0.f;

        const int nkt = 2 * qt + 2;
        for (int kt = 0; kt < nkt; ++kt) {
            const int kv0 = kt * 64;
            __syncthreads();
            gld_lds16(kbase + (size_t)(kv0 + kr)      * INNER_ + kc, &Ks[t * 8]);
            gld_lds16(kbase + (size_t)(kv0 + 32 + kr) * INNER_ + kc, &Ks[4096 + t * 8]);
            gld_lds16(vbase + (size_t)vr        * L_ + kv0 + vc, &Vs[t * 8]);
            gld_lds16(vbase + (size_t)(64 + vr) * L_ + kv0 + vc, &Vs[4096 + t * 8]);
            __syncthreads();

            if (kv0 > rowbase + 15) continue;   // all this wave's rows precede kv0

            // S^T = K . Q^T
            f32x4_t sacc[4];
#pragma unroll
            for (int tt = 0; tt < 4; tt++) sacc[tt] = (f32x4_t){0.f, 0.f, 0.f, 0.f};
#pragma unroll
            for (int kk = 0; kk < 4; kk++) {
                bf16x8_t kf[4];
#pragma unroll
                for (int tt = 0; tt < 4; tt++)
                    kf[tt] = *(const bf16x8_t*)&Ks[(tt * 16 + l16) * 128 + (((kk * 4 + quad) ^ l16) << 3)];
#pragma unroll
                for (int tt = 0; tt < 4; tt++)
                    sacc[tt] = __builtin_amdgcn_mfma_f32_16x16x32_bf16(
                        kf[tt], aq[kk], sacc[tt], 0, 0, 0);
            }

            if (kv0 + 63 > rowbase) {   // diagonal tile: causal mask
                const int qrow = rowbase + l16;
#pragma unroll
                for (int tt = 0; tt < 4; tt++)
#pragma unroll
                    for (int r = 0; r < 4; r++)
                        if (kv0 + tt * 16 + quad * 4 + r > qrow) sacc[tt][r] = -1e30f;
            }

            // online softmax: lane-local 16 + 2 shfl
            float mx = sacc[0][0];
#pragma unroll
            for (int tt = 0; tt < 4; tt++)
#pragma unroll
                for (int r = 0; r < 4; r++) mx = fmaxf(mx, sacc[tt][r]);
            mx = fmaxf(mx, __shfl_xor(mx, 16));
            mx = fmaxf(mx, __shfl_xor(mx, 32));
            const float mnew = fmaxf(m_, mx);
            const float alpha = exp2f(m_ - mnew);
            m_ = mnew;

            float ls = 0.f;
#pragma unroll
            for (int tt = 0; tt < 4; tt++) {
                ushort4 pk;
                float p0 = exp2f(sacc[tt][0] - mnew);
                float p1 = exp2f(sacc[tt][1] - mnew);
                float p2 = exp2f(sacc[tt][2] - mnew);
                float p3 = exp2f(sacc[tt][3] - mnew);
                ls += (p0 + p1) + (p2 + p3);
                pk.x = f2bf(p0); pk.y = f2bf(p1); pk.z = f2bf(p2); pk.w = f2bf(p3);
                *(ushort4*)&Pt[wave][l16 * 72 + tt * 16 + quad * 4] = pk;
            }
            ls += __shfl_xor(ls, 16);
            ls += __shfl_xor(ls, 32);
            l_ = l_ * alpha + ls;
#pragma unroll
            for (int jj = 0; jj < 8; jj++) {
                oacc[jj][0] *= alpha; oacc[jj][1] *= alpha;
                oacc[jj][2] *= alpha; oacc[jj][3] *= alpha;
            }

            // O^T += V^T . P^T
#pragma unroll
            for (int kk2 = 0; kk2 < 2; kk2++) {
                bf16x8_t pf = *(const bf16x8_t*)&Pt[wave][l16 * 72 + kk2 * 32 + quad * 8];
#pragma unroll
                for (int jj = 0; jj < 8; jj++) {
                    bf16x8_t vf = *(const bf16x8_t*)
                        &Vs[(jj * 16 + l16) * 64 + (((kk2 * 4 + quad) ^ (l16 & 7)) << 3)];
                    oacc[jj] = __builtin_amdgcn_mfma_f32_16x16x32_bf16(vf, pf, oacc[jj], 0, 0, 0);
                }
            }
        }

        // epilogue: O^T C-layout -> o[q][h*128+d]; d = jj*16 + quad*4 + r
        {
            const float inv = 1.0f / l_;
            __hip_bfloat16* orow = o + (size_t)(b * L_ + rowbase + l16) * INNER_ + h * DH_;
#pragma unroll
            for (int jj = 0; jj < 8; jj++) {
                ushort4 pk;
                pk.x = f2bf(oacc[jj][0] * inv);
                pk.y = f2bf(oacc[jj][1] * inv);
                pk.z = f2bf(oacc[jj][2] * inv);
                pk.w = f2bf(oacc[jj][3] * inv);
                *(ushort4*)(orow + jj * 16 + quad * 4) = pk;
            }
        }
    }
}

// ---------------------------------------------------------------- launch
extern "C" void kernel_launch(void* const* d_in, const int* in_sizes, int n_in,
                              void* d_out, int out_size, void* d_ws, size_t ws_size,
                              hipStream_t stream) {
    const float* x      = (const float*)d_in[0];
    const float* pe_cos = (const float*)d_in[1];
    const float* pe_sin = (const float*)d_in[2];
    const float* lls    = (const float*)d_in[3];
    const float* wq     = (const float*)d_in[4];
    const float* bq     = (const float*)d_in[5];
    const float* wk     = (const float*)d_in[6];
    const float* bk     = (const float*)d_in[7];
    const float* wv     = (const float*)d_in[8];
    const float* bv     = (const float*)d_in[9];
    const float* qn     = (const float*)d_in[10];
    const float* kn     = (const float*)d_in[11];
    const float* wo     = (const float*)d_in[12];
    const float* bo     = (const float*)d_in[13];

    char* ws = (char*)d_ws;
    const size_t SZ_W = (size_t)D_ * INNER_ * 2;   // 8 MB (bf16)
    const size_t SZ_M = (size_t)M_ * INNER_ * 2;   // 16 MB (bf16)
    __hip_bfloat16* xb     = (__hip_bfloat16*)ws;  ws += SZ_M;
    __hip_bfloat16* wqkvT  = (__hip_bfloat16*)ws;  ws += 3 * SZ_W;  // [6144][2048]
    __hip_bfloat16* woT    = (__hip_bfloat16*)ws;  ws += SZ_W;
    __hip_bfloat16* qb     = (__hip_bfloat16*)ws;  ws += SZ_M;
    __hip_bfloat16* kb     = (__hip_bfloat16*)ws;  ws += SZ_M;
    __hip_bfloat16* vT     = (__hip_bfloat16*)ws;  ws += SZ_M;
    __hip_bfloat16* ab     = (__hip_bfloat16*)ws;  ws += SZ_M;
    (void)in_sizes; (void)n_in; (void)out_size; (void)ws_size;

    const dim3 tb(256);

    // 0. cast x to bf16
    k_cast<<<(M_ * D_) / 1024, tb, 0, stream>>>(x, (unsigned short*)xb);

    // 1. all 4 weight transpose+casts in one dispatch
    k_wtrans4<<<dim3(64, 64, 4), tb, 0, stream>>>(
        wq, wk, wv, wo,
        (unsigned short*)wqkvT,
        (unsigned short*)(wqkvT + (size_t)INNER_ * D_),
        (unsigned short*)(wqkvT + 2 * (size_t)INNER_ * D_),
        (unsigned short*)woT);

    // 2. fused QKV projection; v written directly transposed
    k_gemm_qkv<<<dim3(M_ / 128, 48), tb, 0, stream>>>(xb, wqkvT, bq, bk, bv, qb, kb, vT);

    // 3. RMSNorm + RoPE for q and k in one dispatch
    const float qextra = 0.08838834764831843f /* rsqrt(128) */ * 1.4426950408889634f /* log2 e */;
    k_rmsrope2<<<dim3(M_, 2), tb, 0, stream>>>(qb, kb, qn, kn, pe_cos, pe_sin, lls, qextra);

    // 4. causal flash attention (S^T formulation, 8 waves/block)
    k_attn<<<dim3(8, B_ * H_), dim3(512), 0, stream>>>(qb, kb, vT, ab);

    // 5. output projection -> d_out (f32)
    k_gemm_bt_f32<<<dim3(M_ / 128, D_ / 128), tb, 0, stream>>>(ab, woT, bo, (float*)d_out, M_, D_, INNER_);
}